// Round 11
// baseline (829.906 us; speedup 1.0000x reference)
//
#include <hip/hip_runtime.h>
#include <hip/hip_bf16.h>

#define B_ 8
#define H_ 128
#define W_ 128
#define C_ 128

using f32x4 = __attribute__((ext_vector_type(4))) float;
using s16x8 = __attribute__((ext_vector_type(8))) short;
using us4   = __attribute__((ext_vector_type(4))) unsigned short;

// mish(x) = x * tanh(softplus(x)) = x * (t^2 + 2t) / (t^2 + 2t + 2), t = e^x
__device__ __forceinline__ float mish_f(float x) {
    float t = __expf(fminf(x, 20.0f));
    float u = t * (t + 2.0f);
    return x * u / (u + 2.0f);
}

__device__ __forceinline__ int swz_row(int blk) {
    return ((blk & 7) << 7) | (blk >> 3);
}

// fp32 -> bf16 round-to-nearest-even on raw bits
__device__ __forceinline__ unsigned short f2bf_rne(float x) {
    unsigned u = __builtin_bit_cast(unsigned, x);
    u += 0x7FFFu + ((u >> 16) & 1u);
    return (unsigned short)(u >> 16);
}
__device__ __forceinline__ float bf2f(unsigned short h) {
    unsigned u = ((unsigned)h) << 16;
    return __builtin_bit_cast(float, u);
}
// hw conversion path (RNE, same bits as f2bf_rne for finite inputs)
__device__ __forceinline__ unsigned short f2bf_hw(float x) {
    return __bfloat16_as_ushort(__float2bfloat16(x));
}

// unaligned (4B-aligned) float4 load
__device__ __forceinline__ f32x4 load4u(const float* p) {
    f32x4 v;
    __builtin_memcpy(&v, p, 16);
    return v;
}

// ---------------------------------------------------------------------------
// 1) bilinear backward warp -> bf16 hi/lo planes (consumed by costvol MFMA)
// ---------------------------------------------------------------------------
__global__ __launch_bounds__(256) void warp_kernel(
    const float* __restrict__ nxt, const float* __restrict__ flo,
    unsigned short* __restrict__ nwh, unsigned short* __restrict__ nwl)
{
    const int tid = threadIdx.x;
    const int c   = tid & 127;
    const int pix = blockIdx.x * 2 + (tid >> 7);
    const int b   = pix >> 14;
    const int rem = pix & 16383;
    const int y   = rem >> 7;
    const int x   = rem & 127;

    const float fx = flo[(size_t)pix * 2 + 0];
    const float fy = flo[(size_t)pix * 2 + 1];
    const float xf = (float)x + fx;
    const float yf = (float)y + fy;
    const int x0 = (int)xf;
    const int y0 = (int)yf;
    const int x0c = min(max(x0, 0), W_ - 1);
    const int x1c = min(max(x0 + 1, 0), W_ - 1);
    const int y0c = min(max(y0, 0), H_ - 1);
    const int y1c = min(max(y0 + 1, 0), H_ - 1);
    const float x0f = (float)x0c, x1f = (float)x1c;
    const float y0f = (float)y0c, y1f = (float)y1c;
    const float wa = (x1f - xf) * (y1f - yf);
    const float wb = (x1f - xf) * (yf - y0f);
    const float wc = (xf - x0f) * (y1f - yf);
    const float wd = (xf - x0f) * (yf - y0f);

    const float* base = nxt + (size_t)b * H_ * W_ * C_;
    const float Ia = base[((size_t)y0c * W_ + x0c) * C_ + c];
    const float Ib = base[((size_t)y1c * W_ + x0c) * C_ + c];
    const float Ic = base[((size_t)y0c * W_ + x1c) * C_ + c];
    const float Id = base[((size_t)y1c * W_ + x1c) * C_ + c];
    const float v  = wa * Ia + wb * Ib + wc * Ic + wd * Id;

    const unsigned short h = f2bf_hw(v);
    const unsigned short l = f2bf_hw(v - bf2f(h));
    nwh[(size_t)pix * C_ + c] = h;
    nwl[(size_t)pix * C_ + c] = l;
}

// ---------------------------------------------------------------------------
// 2) cost volume via MFMA, R7 structure (verified: 175 -> <115 us).
//    d-major LDS-staged, slot-XOR swizzle, 8-px zero pads, per-d extraction.
// ---------------------------------------------------------------------------
__global__ __launch_bounds__(1024, 4) void costvol_mfma_kernel(
    const float* __restrict__ prv,
    const unsigned short* __restrict__ nwh,
    const unsigned short* __restrict__ nwl,
    float* __restrict__ cost)
{
    __shared__ __align__(16) unsigned short Nhi[144 * 64];  // 18432 B, swizzled
    __shared__ __align__(16) unsigned short Nlo[144 * 64];  // 18432 B
    __shared__ float scr[8][576];                           // 18432 B

    const int tid  = threadIdx.x;
    const int lane = tid & 63;
    const int wv   = tid >> 6;               // 0..15
    const int w    = wv >> 1;                // x-tile 0..7
    const int nt   = wv & 1;                 // n-half 0..1
    const int r    = swz_row(blockIdx.x);    // b*H + y
    const int y    = r & 127;
    const int b    = r >> 7;
    const int m15  = lane & 15;
    const int kq   = lane >> 4;              // k-group 0..3 (8 ch each)

    // ---- A-frags for all 4 kt (held in regs: 32 VGPR) ----
    const float* pbase = prv + ((size_t)r * W_ + (w * 16 + m15)) * C_ + kq * 8;
    s16x8 ahi[4], alo[4];
    #pragma unroll
    for (int kt = 0; kt < 4; ++kt) {
        const f32x4 p0 = *(const f32x4*)(pbase + kt * 32);
        const f32x4 p1 = *(const f32x4*)(pbase + kt * 32 + 4);
        #pragma unroll
        for (int j = 0; j < 8; ++j) {
            const float f = (j < 4) ? p0[j] : p1[j - 4];
            const unsigned short hh = f2bf_hw(f);
            ahi[kt][j] = (short)hh;
            alo[kt][j] = (short)f2bf_hw(f - bf2f(hh));
        }
    }

    // ---- zero the x-pads once (px 0..7 and 136..143; never rewritten) ----
    {
        const int plane = tid >> 9;          // 0..1
        const int rem   = tid & 511;
        const int side  = rem >> 8;          // 0/1
        const int rem2  = rem & 255;
        const int px    = (side ? 136 : 0) + (rem2 >> 5);
        const int dwi   = rem2 & 31;         // dword within the 128B px row
        unsigned int* dst = (unsigned int*)
            ((plane ? (char*)Nlo : (char*)Nhi) + (size_t)px * 128) + dwi;
        *dst = 0u;
    }
    __syncthreads();

    const int px_mem = (w + nt) * 16 + m15;  // 0..143 (s-position of B col)
    const int swz    = px_mem & 7;
    const int quad   = lane >> 4;

    for (int d = 0; d < 9; ++d) {
        const int q = y + d - 4;
        f32x4 acc = (f32x4){0.f, 0.f, 0.f, 0.f};

        if (q >= 0 && q < H_) {              // block-uniform
            const size_t rowb = ((size_t)(b * H_ + q) * W_) * C_;  // shorts
            #pragma unroll
            for (int kp = 0; kp < 2; ++kp) {
                __syncthreads();             // prev N reads done
                // reg-stage: 2 chunks/thread (load linear, write swizzled)
                #pragma unroll
                for (int s = 0; s < 2; ++s) {
                    const int grp   = wv * 2 + s;        // 0..31
                    const int plane = grp >> 4;          // wave-uniform
                    const int ci    = (grp & 15) * 64 + lane;  // 0..1023
                    const int pxi   = ci >> 3;           // 0..127
                    const int slot  = ci & 7;
                    const unsigned short* src =
                        (plane ? nwl : nwh) + rowb
                        + (size_t)pxi * 128 + kp * 64 + slot * 8;
                    const s16x8 v = *(const s16x8*)src;
                    char* bse = plane ? (char*)Nlo : (char*)Nhi;
                    *(s16x8*)(bse + (size_t)(pxi + 8) * 128
                                  + ((slot ^ (pxi & 7)) * 16)) = v;
                }
                __syncthreads();             // N ready
                #pragma unroll
                for (int j = 0; j < 2; ++j) {
                    const int kt      = kp * 2 + j;
                    const int byteoff = px_mem * 128 + (((j * 4 + kq) ^ swz) * 16);
                    const s16x8 bhi = *(const s16x8*)((const char*)Nhi + byteoff);
                    const s16x8 blo = *(const s16x8*)((const char*)Nlo + byteoff);
                    acc = __builtin_amdgcn_mfma_f32_16x16x32_bf16(alo[kt], bhi, acc, 0, 0, 0);
                    acc = __builtin_amdgcn_mfma_f32_16x16x32_bf16(ahi[kt], blo, acc, 0, 0, 0);
                    acc = __builtin_amdgcn_mfma_f32_16x16x32_bf16(ahi[kt], bhi, acc, 0, 0, 0);
                }
            }
        }

        // ---- per-d band extraction (verified R5 math; zeros when q invalid)
        __syncthreads();                     // prev d's scr reads done
        #pragma unroll
        for (int g = 0; g < 4; ++g)
            scr[w][(quad * 4 + g) * 36 + nt * 16 + m15] = acc[g];
        __syncthreads();                     // scr visible
        #pragma unroll
        for (int p = 0; p < 2; ++p) {
            const int local = lane + 64 * p;
            if (local < 72) {                // 72 outputs per (wave, d)
                const int idx = nt * 72 + local;
                const int xl  = idx / 9;
                const int dx  = idx - xl * 9;
                const float v = scr[w][xl * 37 + dx + 4] * (1.0f / 128.0f);
                cost[((size_t)r * W_ + (w * 16 + xl)) * 81 + d * 9 + dx] = v;
            }
        }
    }
}

// ---------------------------------------------------------------------------
// 3) weight prep: pw[CIN][COUT] fp32 -> bf16 hi/lo B-frag tiles
// ---------------------------------------------------------------------------
__global__ __launch_bounds__(256) void prep_kernel(
    const float* __restrict__ pw, int CIN, int COUT, int NT,
    unsigned short* __restrict__ hi, unsigned short* __restrict__ lo)
{
    const int kt = blockIdx.x / NT;
    const int nt = blockIdx.x - kt * NT;
    #pragma unroll
    for (int s = 0; s < 2; ++s) {
        const int e = threadIdx.x + 256 * s;
        const int n = e >> 5, k = e & 31;
        const int kg = kt * 32 + k, ng = nt * 16 + n;
        const float v = (kg < CIN && ng < COUT) ? pw[(size_t)kg * COUT + ng] : 0.0f;
        const unsigned short h = f2bf_rne(v);
        const unsigned short l = f2bf_rne(v - bf2f(h));
        const size_t o = ((size_t)blockIdx.x * 16 + n) * 32 + k;
        hi[o] = h; lo[o] = l;
    }
}

// ---------------------------------------------------------------------------
// 4) fused depthwise3x3(fp32) + pointwise MFMA (bf16 hi/lo), one block/row.
// R11: R7 dataflow (4ch x 2px task, KSTR=40, direct global loads, 64-VGPR
// budget, nothing crosses a barrier) with the load path reworked:
//  - region resolve hoisted to once per (thread, kt) -> (src, stride)
//  - interior tasks (xb in [2,124], clean region): 12 UNGUARDED batched
//    load4u through 3 row pointers (no branches between loads -> single
//    vmcnt group, ~10x less address/guard VALU)
//  - row validity via block-uniform weight zeroing (wk = rowok ? dwl : 0),
//    numerically identical to V-zeroing
//  - x-edge tasks (xb 0/126) + L0 boundary channel groups (cg 80/208/>=212)
//    keep the guarded gather path (2 warps + one kt straddle group)
// ---------------------------------------------------------------------------
template<int CIN, int COUT, bool ACT, bool IS_L0>
__global__ __launch_bounds__(512, 4) void sepconv_kernel(
    const float* __restrict__ in,
    const float* __restrict__ cost, const float* __restrict__ prv,
    const float* __restrict__ flo,
    const float* __restrict__ dw,
    const unsigned short* __restrict__ Bhi, const unsigned short* __restrict__ Blo,
    const float* __restrict__ bias, float* __restrict__ out)
{
    constexpr int KT   = (CIN + 31) / 32;
    constexpr int KPAD = KT * 32;
    constexpr int NT   = (COUT + 15) / 16;
    constexpr int KSTR = 40;                 // ushort stride per px (80B)
    __shared__ unsigned short Ahi[128 * KSTR];   // 10240 B
    __shared__ unsigned short Alo[128 * KSTR];   // 10240 B
    __shared__ float dwl[9 * KPAD];              // <= 8064 B

    const int tid  = threadIdx.x;
    const int lane = tid & 63;
    const int w    = tid >> 6;               // wave 0..7
    const int r    = swz_row(blockIdx.x);    // b*H + h
    const int h    = r & 127;
    const int b    = r >> 7;

    // depthwise task: co = 4-channel group within 32-chunk, xb = 2-px group
    const int co = (tid & 7) * 4;
    const int xb = (tid >> 3) * 2;           // 0,2,...,126

    // per-row validity (block-uniform) and clamped base pixel index
    bool rowok[3]; int rowpix[3];
    #pragma unroll
    for (int ky = 0; ky < 3; ++ky) {
        const int yy = h + ky - 1;
        rowok[ky]  = (yy >= 0) && (yy < H_);
        rowpix[ky] = (b * H_ + (rowok[ky] ? yy : h)) * W_;
    }

    // stage all depthwise weights once (zero-padded channels)
    for (int i = tid; i < 9 * KPAD; i += 512) {
        const int t = i / KPAD, c = i - t * KPAD;
        dwl[i] = (c < CIN) ? dw[t * CIN + c] : 0.0f;
    }

    f32x4 acc[NT];
    #pragma unroll
    for (int n = 0; n < NT; ++n)
        acc[n] = (f32x4){0.0f, 0.0f, 0.0f, 0.0f};

    __syncthreads();                         // dwl ready

    const int mrow  = w * 16 + (lane & 15);
    const int kq8   = (lane >> 4) * 8;
    const bool xfast = (xb != 0) && (xb != 126);

    for (int kt = 0; kt < KT; ++kt) {
        const int cg = kt * 32 + co;

        // ---- resolve source region once per (thread, kt) ----
        const float* src = nullptr;
        int stride = 0;
        bool fast = xfast;
        if constexpr (IS_L0) {
            if (cg <= 76)                      { src = cost + cg;       stride = 81;  }
            else if (cg >= 84 && cg <= 204)    { src = prv + (cg - 81); stride = 128; }
            else                               { fast = false; }  // 80 / 208 / >=212
        } else {
            src = in + cg; stride = CIN;
        }

        // ---- load input window ----
        f32x4 V[3][4];
        if (fast) {
            // branch-free batched loads: 3 row pointers, 4 px each
            #pragma unroll
            for (int ky = 0; ky < 3; ++ky) {
                const float* p = src + (size_t)(rowpix[ky] + xb - 1) * stride;
                #pragma unroll
                for (int xm = 0; xm < 4; ++xm)
                    V[ky][xm] = load4u(p + (size_t)xm * stride);
            }
        } else {
            // guarded gather path (x-edge tasks, L0 boundary/pad groups)
            #pragma unroll
            for (int ky = 0; ky < 3; ++ky) {
                #pragma unroll
                for (int xm = 0; xm < 4; ++xm) {
                    const int xx = xb - 1 + xm;
                    f32x4 v = (f32x4){0.f, 0.f, 0.f, 0.f};
                    if (xx >= 0 && xx < W_) {
                        const int px = rowpix[ky] + xx;
                        if constexpr (IS_L0) {
                            if (cg <= 76) {
                                v = load4u(cost + (size_t)px * 81 + cg);
                            } else if (cg == 80) {
                                const float* cp = cost + (size_t)px * 81;
                                const float* pp = prv + (size_t)px * 128;
                                v = (f32x4){cp[80], pp[0], pp[1], pp[2]};
                            } else if (cg <= 204) {
                                v = load4u(prv + (size_t)px * 128 + (cg - 81));
                            } else if (cg == 208) {
                                const float* pp = prv + (size_t)px * 128;
                                const float* fp = flo + (size_t)px * 2;
                                v = (f32x4){pp[127], fp[0], fp[1], 0.f};
                            }
                            // cg >= 212: stays zero (padded channels)
                        } else {
                            v = *(const f32x4*)(in + (size_t)px * CIN + cg);
                        }
                    }
                    V[ky][xm] = v;
                }
            }
        }

        // ---- depthwise compute (weights zeroed for invalid rows) ----
        f32x4 a0 = (f32x4){0.f, 0.f, 0.f, 0.f};
        f32x4 a1 = (f32x4){0.f, 0.f, 0.f, 0.f};
        #pragma unroll
        for (int ky = 0; ky < 3; ++ky) {
            const f32x4 z  = (f32x4){0.f, 0.f, 0.f, 0.f};
            const f32x4 w0 = rowok[ky] ? *(const f32x4*)&dwl[(ky * 3 + 0) * KPAD + cg] : z;
            const f32x4 w1 = rowok[ky] ? *(const f32x4*)&dwl[(ky * 3 + 1) * KPAD + cg] : z;
            const f32x4 w2 = rowok[ky] ? *(const f32x4*)&dwl[(ky * 3 + 2) * KPAD + cg] : z;
            a0 += w0 * V[ky][0] + w1 * V[ky][1] + w2 * V[ky][2];
            a1 += w0 * V[ky][1] + w1 * V[ky][2] + w2 * V[ky][3];
        }

        // hi/lo split into registers
        us4 h0, l0, h1, l1;
        #pragma unroll
        for (int j = 0; j < 4; ++j) {
            const unsigned short hh0 = f2bf_hw(a0[j]);
            h0[j] = hh0; l0[j] = f2bf_hw(a0[j] - bf2f(hh0));
            const unsigned short hh1 = f2bf_hw(a1[j]);
            h1[j] = hh1; l1[j] = f2bf_hw(a1[j] - bf2f(hh1));
        }

        __syncthreads();                     // prev MFMA done reading A
        *(us4*)&Ahi[(xb + 0) * KSTR + co] = h0;
        *(us4*)&Ahi[(xb + 1) * KSTR + co] = h1;
        *(us4*)&Alo[(xb + 0) * KSTR + co] = l0;
        *(us4*)&Alo[(xb + 1) * KSTR + co] = l1;
        __syncthreads();                     // A ready for this 32-chunk

        // MFMA sweep: wave w -> M-tile w
        const s16x8 ahi = *(const s16x8*)&Ahi[mrow * KSTR + kq8];
        const s16x8 alo = *(const s16x8*)&Alo[mrow * KSTR + kq8];
        #pragma unroll
        for (int nt = 0; nt < NT; ++nt) {
            const size_t boff = (((size_t)(kt * NT + nt)) * 16 + (lane & 15)) * 32
                              + (size_t)kq8;
            const s16x8 bhi = *(const s16x8*)&Bhi[boff];
            const s16x8 blo = *(const s16x8*)&Blo[boff];
            acc[nt] = __builtin_amdgcn_mfma_f32_16x16x32_bf16(alo, bhi, acc[nt], 0, 0, 0);
            acc[nt] = __builtin_amdgcn_mfma_f32_16x16x32_bf16(ahi, blo, acc[nt], 0, 0, 0);
            acc[nt] = __builtin_amdgcn_mfma_f32_16x16x32_bf16(ahi, bhi, acc[nt], 0, 0, 0);
        }
    }

    // epilogue: C/D layout col=lane&15 (n), row=quad*4+reg (px within tile)
    const int n    = lane & 15;
    const int quad = lane >> 4;
    #pragma unroll
    for (int nt = 0; nt < NT; ++nt) {
        const int o = nt * 16 + n;
        if ((COUT % 16 == 0) || (o < COUT)) {
            const float bv = ACT ? bias[o] : 0.0f;   // L5 has no bias
            #pragma unroll
            for (int reg = 0; reg < 4; ++reg) {
                const int px = w * 16 + quad * 4 + reg;
                const float v = acc[nt][reg] + bv;
                out[((size_t)r * W_ + px) * COUT + o] = ACT ? mish_f(v) : v;
            }
        }
    }
}

// ---------------------------------------------------------------------------
extern "C" void kernel_launch(void* const* d_in, const int* in_sizes, int n_in,
                              void* d_out, int out_size, void* d_ws, size_t ws_size,
                              hipStream_t stream)
{
    (void)in_sizes; (void)n_in; (void)out_size; (void)ws_size;
    const float* prv = (const float*)d_in[0];
    const float* nxt = (const float*)d_in[1];
    const float* flo = (const float*)d_in[2];
    const float* dw0 = (const float*)d_in[3];
    const float* pw0 = (const float*)d_in[4];
    const float* b0  = (const float*)d_in[5];
    const float* dw1 = (const float*)d_in[6];
    const float* pw1 = (const float*)d_in[7];
    const float* b1  = (const float*)d_in[8];
    const float* dw2 = (const float*)d_in[9];
    const float* pw2 = (const float*)d_in[10];
    const float* b2  = (const float*)d_in[11];
    const float* dw3 = (const float*)d_in[12];
    const float* pw3 = (const float*)d_in[13];
    const float* b3  = (const float*)d_in[14];
    const float* dw4 = (const float*)d_in[15];
    const float* pw4 = (const float*)d_in[16];
    const float* b4  = (const float*)d_in[17];
    const float* dw5 = (const float*)d_in[18];
    const float* pw5 = (const float*)d_in[19];

    char* ws = (char*)d_ws;
    float* bufA = (float*)ws;                               // [0, 64Mi)
    float* bufC = (float*)(ws + 67108864);                  // [64Mi, 128Mi)
    float* costb = bufC;                                    // 42.47 MB
    float* l4out = (float*)(ws + 67108864 + 33554432);      // bufC + 32Mi (16 MB)
    float* outp  = (float*)d_out;

    // nxtw bf16 hi/lo planes live in bufA (33.5 MB each, 67.1 MB total = 64Mi)
    unsigned short* nwh = (unsigned short*)ws;
    unsigned short* nwl = (unsigned short*)(ws + 33554432);

    // weight regions (bf16 hi/lo tile arrays)
    unsigned short* W0h = (unsigned short*)(ws + 112000000);            // 57344 B
    unsigned short* W0l = (unsigned short*)(ws + 112000000 + 57344);
    unsigned short* W1h = (unsigned short*)d_out;                       // 32768 B
    unsigned short* W1l = (unsigned short*)d_out + 16384;
    unsigned short* W2h = (unsigned short*)(ws + 50331648);             // 24576 B
    unsigned short* W2l = (unsigned short*)(ws + 50356224);
    unsigned short* W3h = (unsigned short*)(ws + 50380800);             // 12288 B
    unsigned short* W3l = (unsigned short*)(ws + 50393088);
    unsigned short* W4h = (unsigned short*)(ws + 50405376);             //  4096 B
    unsigned short* W4l = (unsigned short*)(ws + 50409472);
    unsigned short* W5h = (unsigned short*)(ws + 50413568);             //  1024 B
    unsigned short* W5l = (unsigned short*)(ws + 50414592);

    const float* nullf = nullptr;

    warp_kernel<<<65536, 256, 0, stream>>>(nxt, flo, nwh, nwl);
    costvol_mfma_kernel<<<1024, 1024, 0, stream>>>(prv, nwh, nwl, costb);

    prep_kernel<<<7 * 8, 256, 0, stream>>>(pw0, 211, 128, 8, W0h, W0l);
    prep_kernel<<<4 * 8, 256, 0, stream>>>(pw1, 128, 128, 8, W1h, W1l);

    // L0: 211 -> 128, reads [cost|prv|flo], writes bufA (nxtw hi/lo dead)
    sepconv_kernel<211, 128, true,  true ><<<1024, 512, 0, stream>>>(
        nullf, costb, prv, flo, dw0, W0h, W0l, b0, bufA);
    // L1: 128 -> 128, bufA -> bufC (cost + W0 dead)
    sepconv_kernel<128, 128, true,  false><<<1024, 512, 0, stream>>>(
        bufA, nullf, nullf, nullf, dw1, W1h, W1l, b1, bufC);

    // bufA now dead -> prep remaining weights into its tail
    prep_kernel<<<4 * 6, 256, 0, stream>>>(pw2, 128,  96, 6, W2h, W2l);
    prep_kernel<<<3 * 4, 256, 0, stream>>>(pw3,  96,  64, 4, W3h, W3l);
    prep_kernel<<<2 * 2, 256, 0, stream>>>(pw4,  64,  32, 2, W4h, W4l);
    prep_kernel<<<1 * 1, 256, 0, stream>>>(pw5,  32,   2, 1, W5h, W5l);

    // L2: 128 -> 96, bufC -> bufA[0,48Mi)
    sepconv_kernel<128,  96, true,  false><<<1024, 512, 0, stream>>>(
        bufC, nullf, nullf, nullf, dw2, W2h, W2l, b2, bufA);
    // L3: 96 -> 64, bufA -> bufC[0,32Mi) (L1 out dead)
    sepconv_kernel< 96,  64, true,  false><<<1024, 512, 0, stream>>>(
        bufA, nullf, nullf, nullf, dw3, W3h, W3l, b3, bufC);
    // L4: 64 -> 32, bufC[0,32Mi) -> bufC[32Mi,48Mi)
    sepconv_kernel< 64,  32, true,  false><<<1024, 512, 0, stream>>>(
        bufC, nullf, nullf, nullf, dw4, W4h, W4l, b4, l4out);
    // L5: 32 -> 2, -> d_out (overwrites W1)
    sepconv_kernel< 32,   2, false, false><<<1024, 512, 0, stream>>>(
        l4out, nullf, nullf, nullf, dw5, W5h, W5l, nullf, outp);
}

// Round 12
// 568.716 us; speedup vs baseline: 1.4593x; 1.4593x over previous
//
#include <hip/hip_runtime.h>
#include <hip/hip_bf16.h>

#define B_ 8
#define H_ 128
#define W_ 128
#define C_ 128

using f32x4 = __attribute__((ext_vector_type(4))) float;
using s16x8 = __attribute__((ext_vector_type(8))) short;
using us4   = __attribute__((ext_vector_type(4))) unsigned short;

// mish(x) = x * tanh(softplus(x)) = x * (t^2 + 2t) / (t^2 + 2t + 2), t = e^x
__device__ __forceinline__ float mish_f(float x) {
    float t = __expf(fminf(x, 20.0f));
    float u = t * (t + 2.0f);
    return x * u / (u + 2.0f);
}

__device__ __forceinline__ int swz_row(int blk) {
    return ((blk & 7) << 7) | (blk >> 3);
}

// fp32 -> bf16 round-to-nearest-even on raw bits
__device__ __forceinline__ unsigned short f2bf_rne(float x) {
    unsigned u = __builtin_bit_cast(unsigned, x);
    u += 0x7FFFu + ((u >> 16) & 1u);
    return (unsigned short)(u >> 16);
}
__device__ __forceinline__ float bf2f(unsigned short h) {
    unsigned u = ((unsigned)h) << 16;
    return __builtin_bit_cast(float, u);
}
// hw conversion path (RNE, same bits as f2bf_rne for finite inputs)
__device__ __forceinline__ unsigned short f2bf_hw(float x) {
    return __bfloat16_as_ushort(__float2bfloat16(x));
}

// unaligned (4B-aligned) float4 load
__device__ __forceinline__ f32x4 load4u(const float* p) {
    f32x4 v;
    __builtin_memcpy(&v, p, 16);
    return v;
}

// ---------------------------------------------------------------------------
// 1) bilinear backward warp -> bf16 hi/lo planes (consumed by costvol MFMA)
// ---------------------------------------------------------------------------
__global__ __launch_bounds__(256) void warp_kernel(
    const float* __restrict__ nxt, const float* __restrict__ flo,
    unsigned short* __restrict__ nwh, unsigned short* __restrict__ nwl)
{
    const int tid = threadIdx.x;
    const int c   = tid & 127;
    const int pix = blockIdx.x * 2 + (tid >> 7);
    const int b   = pix >> 14;
    const int rem = pix & 16383;
    const int y   = rem >> 7;
    const int x   = rem & 127;

    const float fx = flo[(size_t)pix * 2 + 0];
    const float fy = flo[(size_t)pix * 2 + 1];
    const float xf = (float)x + fx;
    const float yf = (float)y + fy;
    const int x0 = (int)xf;
    const int y0 = (int)yf;
    const int x0c = min(max(x0, 0), W_ - 1);
    const int x1c = min(max(x0 + 1, 0), W_ - 1);
    const int y0c = min(max(y0, 0), H_ - 1);
    const int y1c = min(max(y0 + 1, 0), H_ - 1);
    const float x0f = (float)x0c, x1f = (float)x1c;
    const float y0f = (float)y0c, y1f = (float)y1c;
    const float wa = (x1f - xf) * (y1f - yf);
    const float wb = (x1f - xf) * (yf - y0f);
    const float wc = (xf - x0f) * (y1f - yf);
    const float wd = (xf - x0f) * (yf - y0f);

    const float* base = nxt + (size_t)b * H_ * W_ * C_;
    const float Ia = base[((size_t)y0c * W_ + x0c) * C_ + c];
    const float Ib = base[((size_t)y1c * W_ + x0c) * C_ + c];
    const float Ic = base[((size_t)y0c * W_ + x1c) * C_ + c];
    const float Id = base[((size_t)y1c * W_ + x1c) * C_ + c];
    const float v  = wa * Ia + wb * Ib + wc * Ic + wd * Id;

    const unsigned short h = f2bf_hw(v);
    const unsigned short l = f2bf_hw(v - bf2f(h));
    nwh[(size_t)pix * C_ + c] = h;
    nwl[(size_t)pix * C_ + c] = l;
}

// ---------------------------------------------------------------------------
// 2) cost volume via MFMA, R7 structure (verified: 175 -> <115 us).
//    d-major LDS-staged, slot-XOR swizzle, 8-px zero pads, per-d extraction.
// ---------------------------------------------------------------------------
__global__ __launch_bounds__(1024, 4) void costvol_mfma_kernel(
    const float* __restrict__ prv,
    const unsigned short* __restrict__ nwh,
    const unsigned short* __restrict__ nwl,
    float* __restrict__ cost)
{
    __shared__ __align__(16) unsigned short Nhi[144 * 64];  // 18432 B, swizzled
    __shared__ __align__(16) unsigned short Nlo[144 * 64];  // 18432 B
    __shared__ float scr[8][576];                           // 18432 B

    const int tid  = threadIdx.x;
    const int lane = tid & 63;
    const int wv   = tid >> 6;               // 0..15
    const int w    = wv >> 1;                // x-tile 0..7
    const int nt   = wv & 1;                 // n-half 0..1
    const int r    = swz_row(blockIdx.x);    // b*H + y
    const int y    = r & 127;
    const int b    = r >> 7;
    const int m15  = lane & 15;
    const int kq   = lane >> 4;              // k-group 0..3 (8 ch each)

    // ---- A-frags for all 4 kt (held in regs: 32 VGPR) ----
    const float* pbase = prv + ((size_t)r * W_ + (w * 16 + m15)) * C_ + kq * 8;
    s16x8 ahi[4], alo[4];
    #pragma unroll
    for (int kt = 0; kt < 4; ++kt) {
        const f32x4 p0 = *(const f32x4*)(pbase + kt * 32);
        const f32x4 p1 = *(const f32x4*)(pbase + kt * 32 + 4);
        #pragma unroll
        for (int j = 0; j < 8; ++j) {
            const float f = (j < 4) ? p0[j] : p1[j - 4];
            const unsigned short hh = f2bf_hw(f);
            ahi[kt][j] = (short)hh;
            alo[kt][j] = (short)f2bf_hw(f - bf2f(hh));
        }
    }

    // ---- zero the x-pads once (px 0..7 and 136..143; never rewritten) ----
    {
        const int plane = tid >> 9;          // 0..1
        const int rem   = tid & 511;
        const int side  = rem >> 8;          // 0/1
        const int rem2  = rem & 255;
        const int px    = (side ? 136 : 0) + (rem2 >> 5);
        const int dwi   = rem2 & 31;         // dword within the 128B px row
        unsigned int* dst = (unsigned int*)
            ((plane ? (char*)Nlo : (char*)Nhi) + (size_t)px * 128) + dwi;
        *dst = 0u;
    }
    __syncthreads();

    const int px_mem = (w + nt) * 16 + m15;  // 0..143 (s-position of B col)
    const int swz    = px_mem & 7;
    const int quad   = lane >> 4;

    for (int d = 0; d < 9; ++d) {
        const int q = y + d - 4;
        f32x4 acc = (f32x4){0.f, 0.f, 0.f, 0.f};

        if (q >= 0 && q < H_) {              // block-uniform
            const size_t rowb = ((size_t)(b * H_ + q) * W_) * C_;  // shorts
            #pragma unroll
            for (int kp = 0; kp < 2; ++kp) {
                __syncthreads();             // prev N reads done
                // reg-stage: 2 chunks/thread (load linear, write swizzled)
                #pragma unroll
                for (int s = 0; s < 2; ++s) {
                    const int grp   = wv * 2 + s;        // 0..31
                    const int plane = grp >> 4;          // wave-uniform
                    const int ci    = (grp & 15) * 64 + lane;  // 0..1023
                    const int pxi   = ci >> 3;           // 0..127
                    const int slot  = ci & 7;
                    const unsigned short* src =
                        (plane ? nwl : nwh) + rowb
                        + (size_t)pxi * 128 + kp * 64 + slot * 8;
                    const s16x8 v = *(const s16x8*)src;
                    char* bse = plane ? (char*)Nlo : (char*)Nhi;
                    *(s16x8*)(bse + (size_t)(pxi + 8) * 128
                                  + ((slot ^ (pxi & 7)) * 16)) = v;
                }
                __syncthreads();             // N ready
                #pragma unroll
                for (int j = 0; j < 2; ++j) {
                    const int kt      = kp * 2 + j;
                    const int byteoff = px_mem * 128 + (((j * 4 + kq) ^ swz) * 16);
                    const s16x8 bhi = *(const s16x8*)((const char*)Nhi + byteoff);
                    const s16x8 blo = *(const s16x8*)((const char*)Nlo + byteoff);
                    acc = __builtin_amdgcn_mfma_f32_16x16x32_bf16(alo[kt], bhi, acc, 0, 0, 0);
                    acc = __builtin_amdgcn_mfma_f32_16x16x32_bf16(ahi[kt], blo, acc, 0, 0, 0);
                    acc = __builtin_amdgcn_mfma_f32_16x16x32_bf16(ahi[kt], bhi, acc, 0, 0, 0);
                }
            }
        }

        // ---- per-d band extraction (verified R5 math; zeros when q invalid)
        __syncthreads();                     // prev d's scr reads done
        #pragma unroll
        for (int g = 0; g < 4; ++g)
            scr[w][(quad * 4 + g) * 36 + nt * 16 + m15] = acc[g];
        __syncthreads();                     // scr visible
        #pragma unroll
        for (int p = 0; p < 2; ++p) {
            const int local = lane + 64 * p;
            if (local < 72) {                // 72 outputs per (wave, d)
                const int idx = nt * 72 + local;
                const int xl  = idx / 9;
                const int dx  = idx - xl * 9;
                const float v = scr[w][xl * 37 + dx + 4] * (1.0f / 128.0f);
                cost[((size_t)r * W_ + (w * 16 + xl)) * 81 + d * 9 + dx] = v;
            }
        }
    }
}

// ---------------------------------------------------------------------------
// 3) weight prep: pw[CIN][COUT] fp32 -> bf16 hi/lo B-frag tiles
// ---------------------------------------------------------------------------
__global__ __launch_bounds__(256) void prep_kernel(
    const float* __restrict__ pw, int CIN, int COUT, int NT,
    unsigned short* __restrict__ hi, unsigned short* __restrict__ lo)
{
    const int kt = blockIdx.x / NT;
    const int nt = blockIdx.x - kt * NT;
    #pragma unroll
    for (int s = 0; s < 2; ++s) {
        const int e = threadIdx.x + 256 * s;
        const int n = e >> 5, k = e & 31;
        const int kg = kt * 32 + k, ng = nt * 16 + n;
        const float v = (kg < CIN && ng < COUT) ? pw[(size_t)kg * COUT + ng] : 0.0f;
        const unsigned short h = f2bf_rne(v);
        const unsigned short l = f2bf_rne(v - bf2f(h));
        const size_t o = ((size_t)blockIdx.x * 16 + n) * 32 + k;
        hi[o] = h; lo[o] = l;
    }
}

// ---------------------------------------------------------------------------
// 4) fused depthwise3x3(fp32) + pointwise MFMA (bf16 hi/lo), one block/row.
// R12: exact revert to the verified R7 configuration (571 us total; L0 115,
// VGPR 64, no spill). R8-R11 established: with acc[NT] consuming up to 32
// AGPRs of the unified 64-reg budget, ANY load-path restructuring (wider
// tasks, batched unguarded loads, cross-barrier prefetch, forced occupancy)
// spills. The per-load guards here throttle concurrent live loads and keep
// the kernel inside the budget — do not remove them.
// ---------------------------------------------------------------------------
template<int CIN, int COUT, bool ACT, bool IS_L0>
__global__ __launch_bounds__(512, 4) void sepconv_kernel(
    const float* __restrict__ in,
    const float* __restrict__ cost, const float* __restrict__ prv,
    const float* __restrict__ flo,
    const float* __restrict__ dw,
    const unsigned short* __restrict__ Bhi, const unsigned short* __restrict__ Blo,
    const float* __restrict__ bias, float* __restrict__ out)
{
    constexpr int KT   = (CIN + 31) / 32;
    constexpr int KPAD = KT * 32;
    constexpr int NT   = (COUT + 15) / 16;
    constexpr int KSTR = 40;                 // ushort stride per px (80B, 16B-mult)
    __shared__ unsigned short Ahi[128 * KSTR];   // 10240 B
    __shared__ unsigned short Alo[128 * KSTR];   // 10240 B
    __shared__ float dwl[9 * KPAD];              // <= 8064 B

    const int tid  = threadIdx.x;
    const int lane = tid & 63;
    const int w    = tid >> 6;               // wave 0..7
    const int r    = swz_row(blockIdx.x);    // b*H + h
    const int h    = r & 127;
    const int b    = r >> 7;

    // depthwise task: co = 4-channel group within 32-chunk, xb = 2-px group
    const int co = (tid & 7) * 4;
    const int xb = (tid >> 3) * 2;

    // per-row validity (block-uniform) and base pixel index
    bool rowok[3]; int rowpix[3];
    #pragma unroll
    for (int ky = 0; ky < 3; ++ky) {
        const int yy = h + ky - 1;
        rowok[ky]  = (yy >= 0) && (yy < H_);
        rowpix[ky] = (b * H_ + (rowok[ky] ? yy : h)) * W_;
    }

    // stage all depthwise weights once (zero-padded channels)
    for (int i = tid; i < 9 * KPAD; i += 512) {
        const int t = i / KPAD, c = i - t * KPAD;
        dwl[i] = (c < CIN) ? dw[t * CIN + c] : 0.0f;
    }

    f32x4 acc[NT];
    #pragma unroll
    for (int n = 0; n < NT; ++n)
        acc[n] = (f32x4){0.0f, 0.0f, 0.0f, 0.0f};

    __syncthreads();                         // dwl ready

    for (int kt = 0; kt < KT; ++kt) {
        // ---- load input window for this kt (12 float4, issued back-to-back;
        //      overlaps the previous iteration's MFMA drain) ----
        const int cg = kt * 32 + co;
        f32x4 V[3][4];
        #pragma unroll
        for (int ky = 0; ky < 3; ++ky) {
            #pragma unroll
            for (int xm = 0; xm < 4; ++xm) {
                const int xx = xb - 1 + xm;
                f32x4 v = (f32x4){0.f, 0.f, 0.f, 0.f};
                if (rowok[ky] && xx >= 0 && xx < W_) {
                    const int px = rowpix[ky] + xx;
                    if constexpr (IS_L0) {
                        if (cg <= 76) {
                            v = load4u(cost + (size_t)px * 81 + cg);
                        } else if (cg == 80) {
                            const float* cp = cost + (size_t)px * 81;
                            const float* pp = prv + (size_t)px * 128;
                            v = (f32x4){cp[80], pp[0], pp[1], pp[2]};
                        } else if (cg <= 204) {
                            v = load4u(prv + (size_t)px * 128 + (cg - 81));
                        } else if (cg == 208) {
                            const float* pp = prv + (size_t)px * 128;
                            const float* fp = flo + (size_t)px * 2;
                            v = (f32x4){pp[127], fp[0], fp[1], 0.f};
                        }
                        // cg >= 212: stays zero (padded channels)
                    } else {
                        v = *(const f32x4*)(in + (size_t)px * CIN + cg);
                    }
                }
                V[ky][xm] = v;
            }
        }

        // ---- depthwise compute (VALU only) ----
        f32x4 a0 = (f32x4){0.f, 0.f, 0.f, 0.f};
        f32x4 a1 = (f32x4){0.f, 0.f, 0.f, 0.f};
        #pragma unroll
        for (int ky = 0; ky < 3; ++ky) {
            #pragma unroll
            for (int kx = 0; kx < 3; ++kx) {
                const f32x4 wv = *(const f32x4*)&dwl[(ky * 3 + kx) * KPAD + cg];
                a0 += wv * V[ky][kx];
                a1 += wv * V[ky][kx + 1];
            }
        }

        // hi/lo split into registers
        us4 h0, l0, h1, l1;
        #pragma unroll
        for (int j = 0; j < 4; ++j) {
            const unsigned short hh0 = f2bf_hw(a0[j]);
            h0[j] = hh0; l0[j] = f2bf_hw(a0[j] - bf2f(hh0));
            const unsigned short hh1 = f2bf_hw(a1[j]);
            h1[j] = hh1; l1[j] = f2bf_hw(a1[j] - bf2f(hh1));
        }

        __syncthreads();                     // prev MFMA done reading A
        *(us4*)&Ahi[(xb + 0) * KSTR + co] = h0;
        *(us4*)&Ahi[(xb + 1) * KSTR + co] = h1;
        *(us4*)&Alo[(xb + 0) * KSTR + co] = l0;
        *(us4*)&Alo[(xb + 1) * KSTR + co] = l1;
        __syncthreads();                     // A ready for this 32-chunk

        // MFMA sweep: wave w -> M-tile w
        const int mrow = w * 16 + (lane & 15);
        const int ko   = (lane >> 4) * 8;
        const s16x8 ahi = *(const s16x8*)&Ahi[mrow * KSTR + ko];
        const s16x8 alo = *(const s16x8*)&Alo[mrow * KSTR + ko];
        #pragma unroll
        for (int nt = 0; nt < NT; ++nt) {
            const size_t boff = (((size_t)(kt * NT + nt)) * 16 + (lane & 15)) * 32
                              + (size_t)ko;
            const s16x8 bhi = *(const s16x8*)&Bhi[boff];
            const s16x8 blo = *(const s16x8*)&Blo[boff];
            acc[nt] = __builtin_amdgcn_mfma_f32_16x16x32_bf16(alo, bhi, acc[nt], 0, 0, 0);
            acc[nt] = __builtin_amdgcn_mfma_f32_16x16x32_bf16(ahi, blo, acc[nt], 0, 0, 0);
            acc[nt] = __builtin_amdgcn_mfma_f32_16x16x32_bf16(ahi, bhi, acc[nt], 0, 0, 0);
        }
    }

    // epilogue: C/D layout col=lane&15 (n), row=quad*4+reg (px within tile)
    const int n    = lane & 15;
    const int quad = lane >> 4;
    #pragma unroll
    for (int nt = 0; nt < NT; ++nt) {
        const int o = nt * 16 + n;
        if ((COUT % 16 == 0) || (o < COUT)) {
            const float bv = ACT ? bias[o] : 0.0f;   // L5 has no bias
            #pragma unroll
            for (int reg = 0; reg < 4; ++reg) {
                const int px = w * 16 + quad * 4 + reg;
                const float v = acc[nt][reg] + bv;
                out[((size_t)r * W_ + px) * COUT + o] = ACT ? mish_f(v) : v;
            }
        }
    }
}

// ---------------------------------------------------------------------------
extern "C" void kernel_launch(void* const* d_in, const int* in_sizes, int n_in,
                              void* d_out, int out_size, void* d_ws, size_t ws_size,
                              hipStream_t stream)
{
    (void)in_sizes; (void)n_in; (void)out_size; (void)ws_size;
    const float* prv = (const float*)d_in[0];
    const float* nxt = (const float*)d_in[1];
    const float* flo = (const float*)d_in[2];
    const float* dw0 = (const float*)d_in[3];
    const float* pw0 = (const float*)d_in[4];
    const float* b0  = (const float*)d_in[5];
    const float* dw1 = (const float*)d_in[6];
    const float* pw1 = (const float*)d_in[7];
    const float* b1  = (const float*)d_in[8];
    const float* dw2 = (const float*)d_in[9];
    const float* pw2 = (const float*)d_in[10];
    const float* b2  = (const float*)d_in[11];
    const float* dw3 = (const float*)d_in[12];
    const float* pw3 = (const float*)d_in[13];
    const float* b3  = (const float*)d_in[14];
    const float* dw4 = (const float*)d_in[15];
    const float* pw4 = (const float*)d_in[16];
    const float* b4  = (const float*)d_in[17];
    const float* dw5 = (const float*)d_in[18];
    const float* pw5 = (const float*)d_in[19];

    char* ws = (char*)d_ws;
    float* bufA = (float*)ws;                               // [0, 64Mi)
    float* bufC = (float*)(ws + 67108864);                  // [64Mi, 128Mi)
    float* costb = bufC;                                    // 42.47 MB
    float* l4out = (float*)(ws + 67108864 + 33554432);      // bufC + 32Mi (16 MB)
    float* outp  = (float*)d_out;

    // nxtw bf16 hi/lo planes live in bufA (33.5 MB each, 67.1 MB total = 64Mi)
    unsigned short* nwh = (unsigned short*)ws;
    unsigned short* nwl = (unsigned short*)(ws + 33554432);

    // weight regions (bf16 hi/lo tile arrays)
    unsigned short* W0h = (unsigned short*)(ws + 112000000);            // 57344 B
    unsigned short* W0l = (unsigned short*)(ws + 112000000 + 57344);
    unsigned short* W1h = (unsigned short*)d_out;                       // 32768 B
    unsigned short* W1l = (unsigned short*)d_out + 16384;
    unsigned short* W2h = (unsigned short*)(ws + 50331648);             // 24576 B
    unsigned short* W2l = (unsigned short*)(ws + 50356224);
    unsigned short* W3h = (unsigned short*)(ws + 50380800);             // 12288 B
    unsigned short* W3l = (unsigned short*)(ws + 50393088);
    unsigned short* W4h = (unsigned short*)(ws + 50405376);             //  4096 B
    unsigned short* W4l = (unsigned short*)(ws + 50409472);
    unsigned short* W5h = (unsigned short*)(ws + 50413568);             //  1024 B
    unsigned short* W5l = (unsigned short*)(ws + 50414592);

    const float* nullf = nullptr;

    warp_kernel<<<65536, 256, 0, stream>>>(nxt, flo, nwh, nwl);
    costvol_mfma_kernel<<<1024, 1024, 0, stream>>>(prv, nwh, nwl, costb);

    prep_kernel<<<7 * 8, 256, 0, stream>>>(pw0, 211, 128, 8, W0h, W0l);
    prep_kernel<<<4 * 8, 256, 0, stream>>>(pw1, 128, 128, 8, W1h, W1l);

    // L0: 211 -> 128, reads [cost|prv|flo], writes bufA (nxtw hi/lo dead)
    sepconv_kernel<211, 128, true,  true ><<<1024, 512, 0, stream>>>(
        nullf, costb, prv, flo, dw0, W0h, W0l, b0, bufA);
    // L1: 128 -> 128, bufA -> bufC (cost + W0 dead)
    sepconv_kernel<128, 128, true,  false><<<1024, 512, 0, stream>>>(
        bufA, nullf, nullf, nullf, dw1, W1h, W1l, b1, bufC);

    // bufA now dead -> prep remaining weights into its tail
    prep_kernel<<<4 * 6, 256, 0, stream>>>(pw2, 128,  96, 6, W2h, W2l);
    prep_kernel<<<3 * 4, 256, 0, stream>>>(pw3,  96,  64, 4, W3h, W3l);
    prep_kernel<<<2 * 2, 256, 0, stream>>>(pw4,  64,  32, 2, W4h, W4l);
    prep_kernel<<<1 * 1, 256, 0, stream>>>(pw5,  32,   2, 1, W5h, W5l);

    // L2: 128 -> 96, bufC -> bufA[0,48Mi)
    sepconv_kernel<128,  96, true,  false><<<1024, 512, 0, stream>>>(
        bufC, nullf, nullf, nullf, dw2, W2h, W2l, b2, bufA);
    // L3: 96 -> 64, bufA -> bufC[0,32Mi) (L1 out dead)
    sepconv_kernel< 96,  64, true,  false><<<1024, 512, 0, stream>>>(
        bufA, nullf, nullf, nullf, dw3, W3h, W3l, b3, bufC);
    // L4: 64 -> 32, bufC[0,32Mi) -> bufC[32Mi,48Mi)
    sepconv_kernel< 64,  32, true,  false><<<1024, 512, 0, stream>>>(
        bufC, nullf, nullf, nullf, dw4, W4h, W4l, b4, l4out);
    // L5: 32 -> 2, -> d_out (overwrites W1)
    sepconv_kernel< 32,   2, false, false><<<1024, 512, 0, stream>>>(
        l4out, nullf, nullf, nullf, dw5, W5h, W5l, nullf, outp);
}